// Round 14
// baseline (523.926 us; speedup 1.0000x reference)
//
#include <hip/hip_runtime.h>
#include <math.h>

// Problem constants
#define SLEN 1024
#define NH 8
#define DH 64
#define HDIM 512
#define BATCH 16
#define NROWS (BATCH * SLEN)          // 16384
#define BHN (BATCH * NH)              // 128
#define BHROWS (BHN * SLEN)           // 131072

typedef short bf16x8 __attribute__((ext_vector_type(8)));
typedef unsigned short u16x8 __attribute__((ext_vector_type(8)));
typedef float f32x4 __attribute__((ext_vector_type(4)));

__device__ __forceinline__ unsigned short f2bf(float f) {
    unsigned u = __float_as_uint(f);
    u += 0x7fffu + ((u >> 16) & 1u);           // RNE
    return (unsigned short)(u >> 16);
}
__device__ __forceinline__ float bf2f(unsigned short h) {
    return __uint_as_float(((unsigned)h) << 16);
}

// ---------------------------------------------------------------------------
// Workspace layout (BYTE offsets).
//   xbf      @ 0          : 4 x 16,777,216 (xm,xrm,xc,xrc bf16)   [dead after proj]
//   vcat_t   @ 0          : 33,554,432 (aliases xbf[0..2))        [written by vtrans]
//   ctxm     @ 33,554,432 : 16,777,216 bf16 (aliases xbf[2..3))   [written by flash]
//   ctxc     @ 50,331,648 : 16,777,216 bf16 (aliases xbf[3..4))
//   wt       @ 67,108,864 : 8 x 524,288 (W^T bf16 [n][k])
//   sums     @ 71,303,168 : 1,048,576 (qsum|ksum fp32)
//   qcat     @ 72,351,744 : 33,554,432 bf16 [bh][s][128]          [live through flash]
//   kcat     @105,906,176 : 33,554,432                            [dead after flash]
//   vcat     @139,460,608 : 33,554,432                            [dead after vtrans]
// ---------------------------------------------------------------------------
struct Args {
    const float *xm, *xrm, *xc, *xrc;
    const float *w[8], *bias[8];
    const float *ln_w, *ln_b;
    unsigned short *xbf, *wt;
    float *sums;
    unsigned short *qcat, *kcat, *vcat, *vcat_t, *ctxm, *ctxc;
    float *out_m, *out_c, *probs;
};

// ---------------------------------------------------------------------------
// Zero-fill the causal tail of probs: row s, cols [64*((s>>6)+1), 1024).
// 242 MB of pure zeros at streaming BW -- moved OUT of flash_k, whose
// barriers (vmcnt(0) drains) serialized against these stores at ~2.9 TB/s.
// grid (16 bands, 128 bh) x 256; band 15 has no tail.
// ---------------------------------------------------------------------------
__global__ void __launch_bounds__(256) ztail_k(float *probs) {
    const int m = blockIdx.x;          // 64-row band
    const int bh = blockIdx.y;
    const int zc = (m + 1) * 64;       // tail start col
    const int w4 = (SLEN - zc) >> 2;   // f32x4 slots per row
    if (w4 <= 0) return;
    const int t = threadIdx.x;
    const int row = t >> 2;            // 0..63
    float *p = probs + ((size_t)bh * SLEN + m * 64 + row) * SLEN + zc;
    f32x4 z = (f32x4)(0.f);
    for (int s = (t & 3); s < w4; s += 4)
        *(f32x4 *)(p + s * 4) = z;
}

// ---------------------------------------------------------------------------
// Convert the 4 fp32 activation inputs to bf16. grid (4096, 4) x 256.
// ---------------------------------------------------------------------------
__global__ void __launch_bounds__(256) cvt_inputs_k(Args P) {
    const int which = blockIdx.y;
    const float *s = which == 0 ? P.xm : which == 1 ? P.xrm : which == 2 ? P.xc : P.xrc;
    unsigned short *d = P.xbf + (size_t)which * 8388608;
    const long long i = ((long long)blockIdx.x * 256 + threadIdx.x) * 8;
    if (i >= 8388608) return;          // safety guard
    float4 a = *(const float4 *)(s + i);
    float4 b = *(const float4 *)(s + i + 4);
    u16x8 o;
    o[0] = f2bf(a.x); o[1] = f2bf(a.y); o[2] = f2bf(a.z); o[3] = f2bf(a.w);
    o[4] = f2bf(b.x); o[5] = f2bf(b.y); o[6] = f2bf(b.z); o[7] = f2bf(b.w);
    *(u16x8 *)(d + i) = o;
}

// ---------------------------------------------------------------------------
// Transpose+convert the 8 weight matrices: WT[n][k] = bf16(W[k][n]).
// ---------------------------------------------------------------------------
__global__ void __launch_bounds__(256) wtrans_k(Args P) {
    const int op = blockIdx.y;
    const float *W = P.w[op];
    unsigned short *WT = P.wt + (size_t)op * 262144;
    const int kt = blockIdx.x >> 3, nt = blockIdx.x & 7;
    __shared__ float Ws[64][65];
    const int t = threadIdx.x;
#pragma unroll
    for (int it = 0; it < 4; ++it) {
        int g = t + 256 * it;
        int k = g >> 4, n4 = (g & 15) * 4;
        float4 v = *(const float4 *)(W + (size_t)(kt * 64 + k) * 512 + nt * 64 + n4);
        Ws[k][n4] = v.x; Ws[k][n4 + 1] = v.y; Ws[k][n4 + 2] = v.z; Ws[k][n4 + 3] = v.w;
    }
    __syncthreads();
#pragma unroll
    for (int it = 0; it < 2; ++it) {
        int g = t + 256 * it;
        int n = g >> 3, kg = (g & 7) * 8;
        u16x8 o;
#pragma unroll
        for (int e = 0; e < 8; ++e) o[e] = f2bf(Ws[kg + e][n]);
        *(u16x8 *)(WT + (size_t)(nt * 64 + n) * 512 + kt * 64 + kg) = o;
    }
}

// ---------------------------------------------------------------------------
// Projection GEMMs (bf16 MFMA), 128x128 tile, BK=64, 4 waves (2x2, 64x64).
// C = bf16act(Xbf @ WT^T + bias) -> qcat/kcat/vcat [bh][s][128].
// XCD-aware swizzle: each XCD owns a contiguous 16-m-tile chunk (2 MB A slice
// + 0.5 MB WT fit its private 4 MB L2).
// ---------------------------------------------------------------------------
__global__ void __launch_bounds__(256) mgemm0_k(Args P) {
    const int op = blockIdx.z;
    const int srcidx[6] = {0, 0, 1, 2, 2, 3};
    const unsigned short *Abf = P.xbf + (size_t)srcidx[op] * 8388608;
    const unsigned short *WT = P.wt + (size_t)op * 262144;
    const float *bias = P.bias[op];
    unsigned short *dstb; int doff, act;
    switch (op) {
        case 0: dstb = P.qcat; doff = 0;  act = 0; break;
        case 1: dstb = P.kcat; doff = 0;  act = 0; break;
        case 2: dstb = P.vcat; doff = 0;  act = 0; break;
        case 3: dstb = P.qcat; doff = 64; act = 1; break;
        case 4: dstb = P.kcat; doff = 64; act = 1; break;
        default:dstb = P.vcat; doff = 64; act = 2; break;
    }
    // XCD swizzle (dispatch idx % 8 == XCD; 512 blocks per op, 512%8==0)
    const int lin = blockIdx.y * 4 + blockIdx.x;       // 0..511
    const int xcd = lin & 7, idx = lin >> 3;           // idx 0..63
    const int m0 = (xcd * 16 + (idx >> 2)) * 128;
    const int n0 = (idx & 3) * 128;

    __shared__ unsigned short As[128][64];
    __shared__ unsigned short Bs[128][64];
    const int t = threadIdx.x;
    const int wid = t >> 6, lane = t & 63;
    const int wm = wid >> 1, wn = wid & 1;
    const int l16 = lane & 15, lq = lane >> 4;

    f32x4 acc[4][4];
#pragma unroll
    for (int i = 0; i < 4; ++i)
#pragma unroll
        for (int j = 0; j < 4; ++j) acc[i][j] = (f32x4)(0.f);

    for (int k0 = 0; k0 < 512; k0 += 64) {
        __syncthreads();
#pragma unroll
        for (int it = 0; it < 4; ++it) {
            int g = t + 256 * it;
            int r = g >> 3, cg = g & 7;
            bf16x8 av = *(const bf16x8 *)(Abf + (size_t)(m0 + r) * 512 + k0 + cg * 8);
            *(bf16x8 *)&As[r][(cg ^ (r & 7)) * 8] = av;
            bf16x8 bv = *(const bf16x8 *)(WT + (size_t)(n0 + r) * 512 + k0 + cg * 8);
            *(bf16x8 *)&Bs[r][(cg ^ (r & 7)) * 8] = bv;
        }
        __syncthreads();
#pragma unroll
        for (int kk = 0; kk < 2; ++kk) {
            bf16x8 a[4], b[4];
#pragma unroll
            for (int mf = 0; mf < 4; ++mf) {
                int r = wm * 64 + mf * 16 + l16;
                int cg = kk * 4 + lq;
                a[mf] = *(const bf16x8 *)&As[r][(cg ^ (r & 7)) * 8];
            }
#pragma unroll
            for (int nf = 0; nf < 4; ++nf) {
                int r = wn * 64 + nf * 16 + l16;
                int cg = kk * 4 + lq;
                b[nf] = *(const bf16x8 *)&Bs[r][(cg ^ (r & 7)) * 8];
            }
#pragma unroll
            for (int mf = 0; mf < 4; ++mf)
#pragma unroll
                for (int nf = 0; nf < 4; ++nf)
                    acc[mf][nf] = __builtin_amdgcn_mfma_f32_16x16x32_bf16(a[mf], b[nf], acc[mf][nf], 0, 0, 0);
        }
    }

#pragma unroll
    for (int mf = 0; mf < 4; ++mf) {
#pragma unroll
        for (int nf = 0; nf < 4; ++nf) {
#pragma unroll
            for (int r = 0; r < 4; ++r) {
                const int i = m0 + wm * 64 + mf * 16 + lq * 4 + r;
                const int j = n0 + wn * 64 + nf * 16 + l16;
                float v = acc[mf][nf][r] + bias[j];
                if (act == 1) {
                    float e = v > 0.f ? v + 1.f : expf(v);
                    v = sqrtf(fmaxf(e, 1e-24f));
                } else if (act == 2) {
                    v = v > 0.f ? v + 1.f : expf(v);
                }
                const int b_ = i >> 10, s_ = i & (SLEN - 1);
                const int h_ = j >> 6, d_ = j & (DH - 1);
                dstb[((size_t)(b_ * NH + h_) * SLEN + s_) * 128 + doff + d_] = f2bf(v);
            }
        }
    }
}

// ---------------------------------------------------------------------------
// Transpose vcat [bh][s][128] -> vcat_t [bh][d][1024]. grid (8, 128) x 256.
// ---------------------------------------------------------------------------
__global__ void __launch_bounds__(256) vtrans_k(Args P) {
    const int bh = blockIdx.y;
    const int s0 = blockIdx.x * 128;
    __shared__ unsigned short Ts[128][136];
    const unsigned short *src = P.vcat + (size_t)bh * SLEN * 128;
    unsigned short *dst = P.vcat_t + (size_t)bh * 128 * SLEN;
    const int t = threadIdx.x;
#pragma unroll
    for (int it = 0; it < 8; ++it) {
        int g = t + 256 * it;
        int s = g >> 4, dg = g & 15;
        *(u16x8 *)&Ts[s][dg * 8] = *(const u16x8 *)(src + (size_t)(s0 + s) * 128 + dg * 8);
    }
    __syncthreads();
#pragma unroll
    for (int it = 0; it < 8; ++it) {
        int g = t + 256 * it;
        int d = g >> 4, sg = g & 15;
        u16x8 o;
#pragma unroll
        for (int e = 0; e < 8; ++e) o[e] = Ts[sg * 8 + e][d];
        *(u16x8 *)(dst + (size_t)d * SLEN + s0 + sg * 8) = o;
    }
}

// ---------------------------------------------------------------------------
// Row sums from bf16 qcat/kcat (consistent with MFMA operand values).
// ---------------------------------------------------------------------------
__global__ void __launch_bounds__(256) rowsum_k(Args P) {
    const int t = threadIdx.x;
    const int wv = t >> 6, lane = t & 63;
    const long long row = (long long)blockIdx.x * 4 + wv;    // 0..262143
    const unsigned short *src = (row < BHROWS) ? P.qcat : P.kcat;
    const long long r = row & (BHROWS - 1);
    const unsigned short *p = src + r * 128;
    float a = bf2f(p[lane]), b = bf2f(p[64 + lane]);
    float v = a * a + b * b;
#pragma unroll
    for (int o = 32; o > 0; o >>= 1) v += __shfl_xor(v, o);
    if (lane == 0) P.sums[row] = v;
}

// ---------------------------------------------------------------------------
// Fused flash attention (round-14): round-13 structure (32-row q-tiles,
// 512 thr = 8 waves, 80 KB LDS -> 2 blocks/CU, K/V reg-prefetch, interleaved
// probs writes) with:
//  - causal-tail zeros REMOVED (now ztail_k; they serialized at barriers),
//  - exp folded to exp2f (one fewer VALU op/element),
//  - s_setprio(1) around MFMA clusters (T5; 2 blocks/CU gives the scheduler
//    wave role-diversity to arbitrate).
// ---------------------------------------------------------------------------
__global__ void __launch_bounds__(512, 4) flash_k(Args P) {
    const int bh = blockIdx.x;
    const int qt = 31 - (int)blockIdx.y;       // 32-row q tiles, longest first
    const int q0 = qt * 32;
    __shared__ unsigned short Ep[32][1024];    // 64 KB
    __shared__ unsigned short Ks[64][128];     // 16 KB (aliases: T scratch, V tile)
    unsigned short (*Vt)[64] = reinterpret_cast<unsigned short (*)[64]>(&Ks[0][0]);
    float *scr = reinterpret_cast<float *>(&Ks[0][0]);   // [4][32] T partials

    const int t = threadIdx.x;
    const int w = t >> 6, lane = t & 63;
    const int l16 = lane & 15, lq = lane >> 4;
    const int mg = w >> 2, q4 = w & 3;

    const unsigned short *qc = P.qcat + (size_t)bh * SLEN * 128;
    const unsigned short *kc = P.kcat + (size_t)bh * SLEN * 128;
    const float *qsum = P.sums + (size_t)bh * SLEN;
    const float *ksum = P.sums + BHROWS + (size_t)bh * SLEN;
    float *pout = P.probs + ((size_t)bh * SLEN + q0) * SLEN;

    // Q fragments: row = q0 + mg*16 + l16, k-group kk*4+lq (covers 128 dims).
    const unsigned short *qrow = qc + (size_t)(q0 + mg * 16 + l16) * 128;
    bf16x8 qfr[4];
#pragma unroll
    for (int kk = 0; kk < 4; ++kk) qfr[kk] = *(const bf16x8 *)(qrow + (kk * 4 + lq) * 8);
    float qs[4];
#pragma unroll
    for (int r = 0; r < 4; ++r) qs[r] = qsum[q0 + mg * 16 + lq * 4 + r];

    const int nkt = (q0 >> 6) + 1;             // 64-wide k tiles covering <= q0+31
    const int rK = q4 * 16 + l16;
    float tpart[4] = {0.f, 0.f, 0.f, 0.f};
    const float C = 0.18033688f;               // 0.125 * log2(e)

    // ---- Phase 1: masked exp(scores) into the panel, K prefetched ----
    const int sr0 = t >> 4, sg = t & 15;       // K staging rows 0..31 / 32..63
    const int sr1 = sr0 + 32;
    bf16x8 kreg0 = *(const bf16x8 *)(kc + (size_t)sr0 * 128 + sg * 8);
    bf16x8 kreg1 = *(const bf16x8 *)(kc + (size_t)sr1 * 128 + sg * 8);
    float ksreg = ksum[rK];

    for (int kt = 0; kt < nkt; ++kt) {
        __syncthreads();                       // Ks free (prev reads done)
        *(bf16x8 *)&Ks[sr0][(sg ^ (sr0 & 7)) * 8] = kreg0;
        *(bf16x8 *)&Ks[sr1][(sg ^ (sr1 & 7)) * 8] = kreg1;
        if (kt + 1 < nkt) {
            kreg0 = *(const bf16x8 *)(kc + (size_t)((kt + 1) * 64 + sr0) * 128 + sg * 8);
            kreg1 = *(const bf16x8 *)(kc + (size_t)((kt + 1) * 64 + sr1) * 128 + sg * 8);
        }
        __syncthreads();                       // Ks ready

        const float ksv = ksreg;
        if (kt + 1 < nkt) ksreg = ksum[(kt + 1) * 64 + rK];

        __builtin_amdgcn_s_setprio(1);
        f32x4 acc = (f32x4)(0.f);
#pragma unroll
        for (int kk = 0; kk < 4; ++kk) {
            bf16x8 b = *(const bf16x8 *)&Ks[rK][((kk * 4 + lq) ^ (rK & 7)) * 8];
            acc = __builtin_amdgcn_mfma_f32_16x16x32_bf16(qfr[kk], b, acc, 0, 0, 0);
        }
        __builtin_amdgcn_s_setprio(0);
        const int j = kt * 64 + rK;
#pragma unroll
        for (int r = 0; r < 4; ++r) {
            const int row = mg * 16 + lq * 4 + r;
            const int i = q0 + row;
            float sv = (2.f * acc[r] - qs[r] - ksv) * C;
            float e = (j <= i) ? exp2f(sv) : 0.f;
            tpart[r] += e;
            Ep[row][(((j >> 3) ^ (row & 7)) << 3) | (j & 7)] = f2bf(e);
        }
    }

    // ---- Row totals: 16-lane reduce -> scratch (reuses Ks) -> registers ----
#pragma unroll
    for (int o = 1; o < 16; o <<= 1)
#pragma unroll
        for (int r = 0; r < 4; ++r) tpart[r] += __shfl_xor(tpart[r], o);
    __syncthreads();                           // all phase-1 Ks reads complete
    if (l16 == 0) {
#pragma unroll
        for (int r = 0; r < 4; ++r) scr[q4 * 32 + mg * 16 + lq * 4 + r] = tpart[r];
    }
    __syncthreads();
    float invP;                                // 1/T for probs-write row t>>4
    {
        const int row = t >> 4;
        const float T = scr[row] + scr[32 + row] + scr[64 + row] + scr[96 + row];
        invP = (q0 + row == 0) ? 0.f : (1.f / T);
    }
    float invC[4];                             // 1/T for ctx rows mg*16+lq*4+r
#pragma unroll
    for (int r = 0; r < 4; ++r) {
        const int row = mg * 16 + lq * 4 + r;
        const float T = scr[row] + scr[32 + row] + scr[64 + row] + scr[96 + row];
        invC[r] = (q0 + row == 0) ? 0.f : (1.f / T);
    }
    __syncthreads();                           // scratch reads done; V may overwrite

    // ---- Phase 2: PV (V prefetched) + interleaved normalized probs writes --
    const int cov = q4 >> 1;
    f32x4 pacc[2];
    pacc[0] = (f32x4)(0.f); pacc[1] = (f32x4)(0.f);
    const unsigned short *vtg = P.vcat_t + (size_t)bh * 128 * SLEN;
    const int vr0 = t >> 3, vg = t & 7;        // V staging d-rows 0..63 / 64..127
    const int vr1 = vr0 + 64;
    bf16x8 vreg0 = *(const bf16x8 *)(vtg + (size_t)vr0 * SLEN + vg * 8);
    bf16x8 vreg1 = *(const bf16x8 *)(vtg + (size_t)vr1 * SLEN + vg * 8);

    for (int kt = 0; kt < nkt; ++kt) {
        __syncthreads();                       // Vt free
        *(bf16x8 *)&Vt[vr0][(vg ^ (vr0 & 7)) * 8] = vreg0;
        *(bf16x8 *)&Vt[vr1][(vg ^ (vr1 & 7)) * 8] = vreg1;
        if (kt + 1 < nkt) {
            vreg0 = *(const bf16x8 *)(vtg + (size_t)vr0 * SLEN + (kt + 1) * 64 + vg * 8);
            vreg1 = *(const bf16x8 *)(vtg + (size_t)vr1 * SLEN + (kt + 1) * 64 + vg * 8);
        }
        __syncthreads();                       // Vt ready

        __builtin_amdgcn_s_setprio(1);
#pragma unroll
        for (int kk = 0; kk < 2; ++kk) {
            const int row = mg * 16 + l16;
            const int gg = (kt * 8) + kk * 4 + lq;
            bf16x8 af = *(const bf16x8 *)&Ep[row][((gg ^ (row & 7)) << 3)];
            if (cov) {                          // cov operand: elementwise square
                u16x8 u = (u16x8)af, sq;
#pragma unroll
                for (int e = 0; e < 8; ++e) {
                    float f = bf2f(u[e]);
                    sq[e] = f2bf(f * f);
                }
                af = (bf16x8)sq;
            }
#pragma unroll
            for (int nf = 0; nf < 2; ++nf) {
                const int d = q4 * 32 + nf * 16 + l16;
                bf16x8 bf = *(const bf16x8 *)&Vt[d][((kk * 4 + lq) ^ (d & 7)) * 8];
                pacc[nf] = __builtin_amdgcn_mfma_f32_16x16x32_bf16(af, bf, pacc[nf], 0, 0, 0);
            }
        }
        __builtin_amdgcn_s_setprio(0);

        // normalized probs write for tile kt (mask only on the diagonal tile)
        {
            const int prow = t >> 4, slot = t & 15;
            const int col = kt * 64 + slot * 4;
            const int g = col >> 3, o4 = (slot & 1) * 4;
            u16x8 v = *(const u16x8 *)&Ep[prow][((g ^ (prow & 7)) << 3)];
            f32x4 ov;
            if (kt == nkt - 1) {
                const int i = q0 + prow;
#pragma unroll
                for (int e = 0; e < 4; ++e)
                    ov[e] = (col + e <= i) ? bf2f(v[o4 + e]) * invP : 0.f;
            } else {
#pragma unroll
                for (int e = 0; e < 4; ++e)
                    ov[e] = bf2f(v[o4 + e]) * invP;
            }
            *(f32x4 *)(pout + (size_t)prow * SLEN + col) = ov;
        }
    }

    unsigned short *dst = cov ? P.ctxc : P.ctxm;
    const int b_ = bh >> 3, h_ = bh & 7;
#pragma unroll
    for (int nf = 0; nf < 2; ++nf) {
#pragma unroll
        for (int r = 0; r < 4; ++r) {
            const int row = mg * 16 + lq * 4 + r;
            const int s_ = q0 + row;
            const float scale = cov ? invC[r] * invC[r] : invC[r];  // /T or /T^2
            dst[((size_t)b_ * SLEN + s_) * HDIM + h_ * 64 + (q4 & 1) * 32 + nf * 16 + l16] =
                f2bf(pacc[nf][r] * scale);
        }
    }
}

// ---------------------------------------------------------------------------
// Fused output GEMM + bias + residual + LayerNorm.
// out = LN(ctx @ WT^T + bias + resid).  Tile 64(M) x 512(N, full row), BK=64.
// 512 threads = 8 waves (2 m-bands x 4 n-bands); each wave 32x128 output.
// grid (256 m-tiles, 2 ops).
// ---------------------------------------------------------------------------
__global__ void __launch_bounds__(512, 4) mgemm_ln_k(Args P) {
    const int op = blockIdx.y;
    const unsigned short *Abf = op ? P.ctxc : P.ctxm;
    const unsigned short *WT = P.wt + (size_t)(6 + op) * 262144;
    const float *bias = P.bias[6 + op];
    const float *resid = op ? P.xc : P.xm;
    float *out = op ? P.out_c : P.out_m;
    const int m0 = blockIdx.x * 64;

    __shared__ unsigned short As[64][64];      // 8 KB
    __shared__ unsigned short Bs[512][64];     // 64 KB
    __shared__ float Red[64][4][2];            // 2 KB

    const int t = threadIdx.x;
    const int w = t >> 6, lane = t & 63;
    const int wm = w >> 2, wn = w & 3;         // 2 x 4 waves
    const int l16 = lane & 15, lq = lane >> 4;

    f32x4 acc[2][8];
#pragma unroll
    for (int mf = 0; mf < 2; ++mf)
#pragma unroll
        for (int nf = 0; nf < 8; ++nf) acc[mf][nf] = (f32x4)(0.f);

    for (int k0 = 0; k0 < 512; k0 += 64) {
        __syncthreads();
        {   // stage A: 64 rows x 8 groups = 512 slots, 1/thread
            int r = t >> 3, cg = t & 7;
            *(bf16x8 *)&As[r][(cg ^ (r & 7)) * 8] =
                *(const bf16x8 *)(Abf + (size_t)(m0 + r) * 512 + k0 + cg * 8);
        }
#pragma unroll
        for (int it = 0; it < 8; ++it) {       // stage B: 512 rows x 8 groups
            int g = t + 512 * it;
            int r = g >> 3, cg = g & 7;
            *(bf16x8 *)&Bs[r][(cg ^ (r & 7)) * 8] =
                *(const bf16x8 *)(WT + (size_t)r * 512 + k0 + cg * 8);
        }
        __syncthreads();
#pragma unroll
        for (int kk = 0; kk < 2; ++kk) {
            bf16x8 a[2];
#pragma unroll
            for (int mf = 0; mf < 2; ++mf) {
                int r = wm * 32 + mf * 16 + l16;
                a[mf] = *(const bf16x8 *)&As[r][((kk * 4 + lq) ^ (r & 7)) * 8];
            }
#pragma unroll
            for (int nf = 0; nf < 8; ++nf) {
                int rn = wn * 128 + nf * 16 + l16;
                bf16x8 b = *(const bf16x8 *)&Bs[rn][((kk * 4 + lq) ^ (rn & 7)) * 8];
#pragma unroll
                for (int mf = 0; mf < 2; ++mf)
                    acc[mf][nf] = __builtin_amdgcn_mfma_f32_16x16x32_bf16(a[mf], b, acc[mf][nf], 0, 0, 0);
            }
        }
    }

    // epilogue: bias + resid accumulated in place; LN partials per (mf,r)
    float bv[8];
#pragma unroll
    for (int nf = 0; nf < 8; ++nf) bv[nf] = bias[wn * 128 + nf * 16 + l16];

    float s0[2][4], s1[2][4];
#pragma unroll
    for (int mf = 0; mf < 2; ++mf)
#pragma unroll
        for (int r = 0; r < 4; ++r) { s0[mf][r] = 0.f; s1[mf][r] = 0.f; }

#pragma unroll
    for (int mf = 0; mf < 2; ++mf) {
#pragma unroll
        for (int r = 0; r < 4; ++r) {
            const int i = m0 + wm * 32 + mf * 16 + lq * 4 + r;
            const float *rrow = resid + (size_t)i * HDIM + wn * 128 + l16;
#pragma unroll
            for (int nf = 0; nf < 8; ++nf) {
                float x = acc[mf][nf][r] + bv[nf] + rrow[nf * 16];
                acc[mf][nf][r] = x;
                s0[mf][r] += x;
                s1[mf][r] += x * x;
            }
        }
    }
#pragma unroll
    for (int o = 1; o < 16; o <<= 1)
#pragma unroll
        for (int mf = 0; mf < 2; ++mf)
#pragma unroll
            for (int r = 0; r < 4; ++r) {
                s0[mf][r] += __shfl_xor(s0[mf][r], o);
                s1[mf][r] += __shfl_xor(s1[mf][r], o);
            }
    if (l16 == 0) {
#pragma unroll
        for (int mf = 0; mf < 2; ++mf)
#pragma unroll
            for (int r = 0; r < 4; ++r) {
                const int row = wm * 32 + mf * 16 + lq * 4 + r;
                Red[row][wn][0] = s0[mf][r];
                Red[row][wn][1] = s1[mf][r];
            }
    }
    __syncthreads();

    float lnw[8], lnb[8];
#pragma unroll
    for (int nf = 0; nf < 8; ++nf) {
        const int j = wn * 128 + nf * 16 + l16;
        lnw[nf] = P.ln_w[j]; lnb[nf] = P.ln_b[j];
    }
#pragma unroll
    for (int mf = 0; mf < 2; ++mf) {
#pragma unroll
        for (int r = 0; r < 4; ++r) {
            const int row = wm * 32 + mf * 16 + lq * 4 + r;
            const int i = m0 + row;
            const float S  = Red[row][0][0] + Red[row][1][0] + Red[row][2][0] + Red[row][3][0];
            const float SS = Red[row][0][1] + Red[row][1][1] + Red[row][2][1] + Red[row][3][1];
            const float mean = S * (1.f / 512.f);
            const float var = SS * (1.f / 512.f) - mean * mean;
            const float inv = 1.f / sqrtf(var + 1e-12f);
            float *orow = out + (size_t)i * HDIM + wn * 128 + l16;
#pragma unroll
            for (int nf = 0; nf < 8; ++nf)
                orow[nf * 16] = lnw[nf] * ((acc[mf][nf][r] - mean) * inv) + lnb[nf];
        }
    }
}

// ---------------------------------------------------------------------------
extern "C" void kernel_launch(void *const *d_in, const int *in_sizes, int n_in,
                              void *d_out, int out_size, void *d_ws, size_t ws_size,
                              hipStream_t stream) {
    (void)in_sizes; (void)n_in; (void)out_size; (void)ws_size;
    Args P;
    P.xm  = (const float *)d_in[0];
    P.xrm = (const float *)d_in[1];
    P.xc  = (const float *)d_in[2];
    P.xrc = (const float *)d_in[3];
    // d_in[4] = attn_mask: exactly where(causal,0,-1e4); the -1e4 branch
    // underflows to an exact 0 probability, reproduced by causal handling.
    for (int i = 0; i < 8; ++i) {
        P.w[i]    = (const float *)d_in[5 + 2 * i];
        P.bias[i] = (const float *)d_in[6 + 2 * i];
    }
    P.ln_w = (const float *)d_in[21];
    P.ln_b = (const float *)d_in[22];

    char *ws = (char *)d_ws;
    P.xbf    = (unsigned short *)(ws);
    P.vcat_t = (unsigned short *)(ws);                 // alias xbf[0..2) (dead)
    P.ctxm   = (unsigned short *)(ws + 33554432);      // alias xbf[2..3) (dead)
    P.ctxc   = (unsigned short *)(ws + 50331648);      // alias xbf[3..4) (dead)
    P.wt     = (unsigned short *)(ws + 67108864);
    P.sums   = (float *)(ws + 71303168);
    P.qcat   = (unsigned short *)(ws + 72351744);      // live through flash_k
    P.kcat   = (unsigned short *)(ws + 105906176);
    P.vcat   = (unsigned short *)(ws + 139460608);

    P.out_m = (float *)d_out;
    P.out_c = (float *)d_out + 8388608;
    P.probs = (float *)d_out + 16777216;

    ztail_k<<<dim3(16, 128), dim3(256), 0, stream>>>(P.probs);
    cvt_inputs_k<<<dim3(4096, 4), dim3(256), 0, stream>>>(P);
    wtrans_k<<<dim3(64, 8), dim3(256), 0, stream>>>(P);
    mgemm0_k<<<dim3(4, 128, 6), dim3(256), 0, stream>>>(P);
    vtrans_k<<<dim3(8, 128), dim3(256), 0, stream>>>(P);
    rowsum_k<<<dim3(65536), dim3(256), 0, stream>>>(P);
    flash_k<<<dim3(128, 32), dim3(512), 0, stream>>>(P);
    mgemm_ln_k<<<dim3(256, 2), dim3(512), 0, stream>>>(P);
}

// Round 15
// 466.510 us; speedup vs baseline: 1.1231x; 1.1231x over previous
//
#include <hip/hip_runtime.h>
#include <math.h>

// Problem constants
#define SLEN 1024
#define NH 8
#define DH 64
#define HDIM 512
#define BATCH 16
#define NROWS (BATCH * SLEN)          // 16384
#define BHN (BATCH * NH)              // 128
#define BHROWS (BHN * SLEN)           // 131072

typedef short bf16x8 __attribute__((ext_vector_type(8)));
typedef unsigned short u16x8 __attribute__((ext_vector_type(8)));
typedef float f32x4 __attribute__((ext_vector_type(4)));

__device__ __forceinline__ unsigned short f2bf(float f) {
    unsigned u = __float_as_uint(f);
    u += 0x7fffu + ((u >> 16) & 1u);           // RNE
    return (unsigned short)(u >> 16);
}
__device__ __forceinline__ float bf2f(unsigned short h) {
    return __uint_as_float(((unsigned)h) << 16);
}

// Async global->LDS 16B copy: per-lane global src, wave-uniform LDS base
// (HW writes at base + lane*16). Drained by the vmcnt(0) in __syncthreads.
__device__ __forceinline__ void gload16(const void *g, void *l) {
    __builtin_amdgcn_global_load_lds(
        (const __attribute__((address_space(1))) unsigned int *)g,
        (__attribute__((address_space(3))) unsigned int *)l,
        16, 0, 0);
}

// ---------------------------------------------------------------------------
// Workspace layout (BYTE offsets).
//   xbf      @ 0          : 4 x 16,777,216 (xm,xrm,xc,xrc bf16)   [dead after proj]
//   vcat_t   @ 0          : 33,554,432 (aliases xbf[0..2))        [written by vtrans]
//   ctxm     @ 33,554,432 : 16,777,216 bf16 (aliases xbf[2..3))   [written by flash]
//   ctxc     @ 50,331,648 : 16,777,216 bf16 (aliases xbf[3..4))
//   wt       @ 67,108,864 : 8 x 524,288 (W^T bf16 [n][k])
//   sums     @ 71,303,168 : 1,048,576 (qsum|ksum fp32)
//   qcat     @ 72,351,744 : 33,554,432 bf16 [bh][s][128]          [live through flash]
//   kcat     @105,906,176 : 33,554,432                            [dead after flash]
//   vcat     @139,460,608 : 33,554,432                            [dead after vtrans]
// ---------------------------------------------------------------------------
struct Args {
    const float *xm, *xrm, *xc, *xrc;
    const float *w[8], *bias[8];
    const float *ln_w, *ln_b;
    unsigned short *xbf, *wt;
    float *sums;
    unsigned short *qcat, *kcat, *vcat, *vcat_t, *ctxm, *ctxc;
    float *out_m, *out_c, *probs;
};

// ---------------------------------------------------------------------------
// Convert the 4 fp32 activation inputs to bf16. grid (4096, 4) x 256.
// ---------------------------------------------------------------------------
__global__ void __launch_bounds__(256) cvt_inputs_k(Args P) {
    const int which = blockIdx.y;
    const float *s = which == 0 ? P.xm : which == 1 ? P.xrm : which == 2 ? P.xc : P.xrc;
    unsigned short *d = P.xbf + (size_t)which * 8388608;
    const long long i = ((long long)blockIdx.x * 256 + threadIdx.x) * 8;
    if (i >= 8388608) return;          // safety guard
    float4 a = *(const float4 *)(s + i);
    float4 b = *(const float4 *)(s + i + 4);
    u16x8 o;
    o[0] = f2bf(a.x); o[1] = f2bf(a.y); o[2] = f2bf(a.z); o[3] = f2bf(a.w);
    o[4] = f2bf(b.x); o[5] = f2bf(b.y); o[6] = f2bf(b.z); o[7] = f2bf(b.w);
    *(u16x8 *)(d + i) = o;
}

// ---------------------------------------------------------------------------
// Transpose+convert the 8 weight matrices: WT[n][k] = bf16(W[k][n]).
// ---------------------------------------------------------------------------
__global__ void __launch_bounds__(256) wtrans_k(Args P) {
    const int op = blockIdx.y;
    const float *W = P.w[op];
    unsigned short *WT = P.wt + (size_t)op * 262144;
    const int kt = blockIdx.x >> 3, nt = blockIdx.x & 7;
    __shared__ float Ws[64][65];
    const int t = threadIdx.x;
#pragma unroll
    for (int it = 0; it < 4; ++it) {
        int g = t + 256 * it;
        int k = g >> 4, n4 = (g & 15) * 4;
        float4 v = *(const float4 *)(W + (size_t)(kt * 64 + k) * 512 + nt * 64 + n4);
        Ws[k][n4] = v.x; Ws[k][n4 + 1] = v.y; Ws[k][n4 + 2] = v.z; Ws[k][n4 + 3] = v.w;
    }
    __syncthreads();
#pragma unroll
    for (int it = 0; it < 2; ++it) {
        int g = t + 256 * it;
        int n = g >> 3, kg = (g & 7) * 8;
        u16x8 o;
#pragma unroll
        for (int e = 0; e < 8; ++e) o[e] = f2bf(Ws[kg + e][n]);
        *(u16x8 *)(WT + (size_t)(nt * 64 + n) * 512 + kt * 64 + kg) = o;
    }
}

// ---------------------------------------------------------------------------
// Projection GEMMs (bf16 MFMA), 128x128 tile, BK=64, 4 waves (2x2, 64x64).
// C = bf16act(Xbf @ WT^T + bias) -> qcat/kcat/vcat [bh][s][128].
// XCD-aware swizzle; round-15: staging via global_load_lds width-16 with
// PRE-SWIZZLED global source (XOR cg^(r&7) is an involution, so the LDS
// image As[r][X] = global[X^(r&7)] is unchanged -- readers untouched).
// ---------------------------------------------------------------------------
__global__ void __launch_bounds__(256) mgemm0_k(Args P) {
    const int op = blockIdx.z;
    const int srcidx[6] = {0, 0, 1, 2, 2, 3};
    const unsigned short *Abf = P.xbf + (size_t)srcidx[op] * 8388608;
    const unsigned short *WT = P.wt + (size_t)op * 262144;
    const float *bias = P.bias[op];
    unsigned short *dstb; int doff, act;
    switch (op) {
        case 0: dstb = P.qcat; doff = 0;  act = 0; break;
        case 1: dstb = P.kcat; doff = 0;  act = 0; break;
        case 2: dstb = P.vcat; doff = 0;  act = 0; break;
        case 3: dstb = P.qcat; doff = 64; act = 1; break;
        case 4: dstb = P.kcat; doff = 64; act = 1; break;
        default:dstb = P.vcat; doff = 64; act = 2; break;
    }
    // XCD swizzle (dispatch idx % 8 == XCD; 512 blocks per op, 512%8==0)
    const int lin = blockIdx.y * 4 + blockIdx.x;       // 0..511
    const int xcd = lin & 7, idx = lin >> 3;           // idx 0..63
    const int m0 = (xcd * 16 + (idx >> 2)) * 128;
    const int n0 = (idx & 3) * 128;

    __shared__ unsigned short As[128][64];
    __shared__ unsigned short Bs[128][64];
    const int t = threadIdx.x;
    const int wid = t >> 6, lane = t & 63;
    const int wm = wid >> 1, wn = wid & 1;
    const int l16 = lane & 15, lq = lane >> 4;
    char *AsB = (char *)&As[0][0];
    char *BsB = (char *)&Bs[0][0];

    f32x4 acc[4][4];
#pragma unroll
    for (int i = 0; i < 4; ++i)
#pragma unroll
        for (int j = 0; j < 4; ++j) acc[i][j] = (f32x4)(0.f);

    for (int k0 = 0; k0 < 512; k0 += 64) {
        __syncthreads();
#pragma unroll
        for (int it = 0; it < 4; ++it) {
            int g = t + 256 * it;
            int r = g >> 3, cg = g & 7;
            int sc = (cg ^ (r & 7)) * 8;       // pre-swizzled source group
            gload16(Abf + (size_t)(m0 + r) * 512 + k0 + sc, AsB + it * 4096 + wid * 1024);
            gload16(WT + (size_t)(n0 + r) * 512 + k0 + sc, BsB + it * 4096 + wid * 1024);
        }
        __syncthreads();
#pragma unroll
        for (int kk = 0; kk < 2; ++kk) {
            bf16x8 a[4], b[4];
#pragma unroll
            for (int mf = 0; mf < 4; ++mf) {
                int r = wm * 64 + mf * 16 + l16;
                int cg = kk * 4 + lq;
                a[mf] = *(const bf16x8 *)&As[r][(cg ^ (r & 7)) * 8];
            }
#pragma unroll
            for (int nf = 0; nf < 4; ++nf) {
                int r = wn * 64 + nf * 16 + l16;
                int cg = kk * 4 + lq;
                b[nf] = *(const bf16x8 *)&Bs[r][(cg ^ (r & 7)) * 8];
            }
#pragma unroll
            for (int mf = 0; mf < 4; ++mf)
#pragma unroll
                for (int nf = 0; nf < 4; ++nf)
                    acc[mf][nf] = __builtin_amdgcn_mfma_f32_16x16x32_bf16(a[mf], b[nf], acc[mf][nf], 0, 0, 0);
        }
    }

#pragma unroll
    for (int mf = 0; mf < 4; ++mf) {
#pragma unroll
        for (int nf = 0; nf < 4; ++nf) {
#pragma unroll
            for (int r = 0; r < 4; ++r) {
                const int i = m0 + wm * 64 + mf * 16 + lq * 4 + r;
                const int j = n0 + wn * 64 + nf * 16 + l16;
                float v = acc[mf][nf][r] + bias[j];
                if (act == 1) {
                    float e = v > 0.f ? v + 1.f : expf(v);
                    v = sqrtf(fmaxf(e, 1e-24f));
                } else if (act == 2) {
                    v = v > 0.f ? v + 1.f : expf(v);
                }
                const int b_ = i >> 10, s_ = i & (SLEN - 1);
                const int h_ = j >> 6, d_ = j & (DH - 1);
                dstb[((size_t)(b_ * NH + h_) * SLEN + s_) * 128 + doff + d_] = f2bf(v);
            }
        }
    }
}

// ---------------------------------------------------------------------------
// Transpose vcat [bh][s][128] -> vcat_t [bh][d][1024]. grid (8, 128) x 256.
// ---------------------------------------------------------------------------
__global__ void __launch_bounds__(256) vtrans_k(Args P) {
    const int bh = blockIdx.y;
    const int s0 = blockIdx.x * 128;
    __shared__ unsigned short Ts[128][136];
    const unsigned short *src = P.vcat + (size_t)bh * SLEN * 128;
    unsigned short *dst = P.vcat_t + (size_t)bh * 128 * SLEN;
    const int t = threadIdx.x;
#pragma unroll
    for (int it = 0; it < 8; ++it) {
        int g = t + 256 * it;
        int s = g >> 4, dg = g & 15;
        *(u16x8 *)&Ts[s][dg * 8] = *(const u16x8 *)(src + (size_t)(s0 + s) * 128 + dg * 8);
    }
    __syncthreads();
#pragma unroll
    for (int it = 0; it < 8; ++it) {
        int g = t + 256 * it;
        int d = g >> 4, sg = g & 15;
        u16x8 o;
#pragma unroll
        for (int e = 0; e < 8; ++e) o[e] = Ts[sg * 8 + e][d];
        *(u16x8 *)(dst + (size_t)d * SLEN + s0 + sg * 8) = o;
    }
}

// ---------------------------------------------------------------------------
// Row sums from bf16 qcat/kcat (consistent with MFMA operand values).
// ---------------------------------------------------------------------------
__global__ void __launch_bounds__(256) rowsum_k(Args P) {
    const int t = threadIdx.x;
    const int wv = t >> 6, lane = t & 63;
    const long long row = (long long)blockIdx.x * 4 + wv;    // 0..262143
    const unsigned short *src = (row < BHROWS) ? P.qcat : P.kcat;
    const long long r = row & (BHROWS - 1);
    const unsigned short *p = src + r * 128;
    float a = bf2f(p[lane]), b = bf2f(p[64 + lane]);
    float v = a * a + b * b;
#pragma unroll
    for (int o = 32; o > 0; o >>= 1) v += __shfl_xor(v, o);
    if (lane == 0) P.sums[row] = v;
}

// ---------------------------------------------------------------------------
// Fused flash attention (round-15 = round-13 structure + exp2f + setprio):
// 32-row q-tiles, 512 thr = 8 waves, 80 KB LDS -> 2 blocks/CU, K/V
// reg-prefetch, interleaved probs writes, IN-FLASH causal-tail zeros
// (round-14's separate ztail_k cost +44us -> reverted).
// ---------------------------------------------------------------------------
__global__ void __launch_bounds__(512, 4) flash_k(Args P) {
    const int bh = blockIdx.x;
    const int qt = 31 - (int)blockIdx.y;       // 32-row q tiles, longest first
    const int q0 = qt * 32;
    __shared__ unsigned short Ep[32][1024];    // 64 KB
    __shared__ unsigned short Ks[64][128];     // 16 KB (aliases: T scratch, V tile)
    unsigned short (*Vt)[64] = reinterpret_cast<unsigned short (*)[64]>(&Ks[0][0]);
    float *scr = reinterpret_cast<float *>(&Ks[0][0]);   // [4][32] T partials

    const int t = threadIdx.x;
    const int w = t >> 6, lane = t & 63;
    const int l16 = lane & 15, lq = lane >> 4;
    const int mg = w >> 2, q4 = w & 3;

    const unsigned short *qc = P.qcat + (size_t)bh * SLEN * 128;
    const unsigned short *kc = P.kcat + (size_t)bh * SLEN * 128;
    const float *qsum = P.sums + (size_t)bh * SLEN;
    const float *ksum = P.sums + BHROWS + (size_t)bh * SLEN;
    float *pout = P.probs + ((size_t)bh * SLEN + q0) * SLEN;

    // Q fragments: row = q0 + mg*16 + l16, k-group kk*4+lq (covers 128 dims).
    const unsigned short *qrow = qc + (size_t)(q0 + mg * 16 + l16) * 128;
    bf16x8 qfr[4];
#pragma unroll
    for (int kk = 0; kk < 4; ++kk) qfr[kk] = *(const bf16x8 *)(qrow + (kk * 4 + lq) * 8);
    float qs[4];
#pragma unroll
    for (int r = 0; r < 4; ++r) qs[r] = qsum[q0 + mg * 16 + lq * 4 + r];

    const int nkt = (q0 >> 6) + 1;             // 64-wide k tiles covering <= q0+31
    const int rK = q4 * 16 + l16;
    float tpart[4] = {0.f, 0.f, 0.f, 0.f};
    const float C = 0.18033688f;               // 0.125 * log2(e)

    // ---- Phase 1: masked exp(scores) into the panel, K prefetched ----
    const int sr0 = t >> 4, sg = t & 15;       // K staging rows 0..31 / 32..63
    const int sr1 = sr0 + 32;
    bf16x8 kreg0 = *(const bf16x8 *)(kc + (size_t)sr0 * 128 + sg * 8);
    bf16x8 kreg1 = *(const bf16x8 *)(kc + (size_t)sr1 * 128 + sg * 8);
    float ksreg = ksum[rK];

    for (int kt = 0; kt < nkt; ++kt) {
        __syncthreads();                       // Ks free (prev reads done)
        *(bf16x8 *)&Ks[sr0][(sg ^ (sr0 & 7)) * 8] = kreg0;
        *(bf16x8 *)&Ks[sr1][(sg ^ (sr1 & 7)) * 8] = kreg1;
        if (kt + 1 < nkt) {
            kreg0 = *(const bf16x8 *)(kc + (size_t)((kt + 1) * 64 + sr0) * 128 + sg * 8);
            kreg1 = *(const bf16x8 *)(kc + (size_t)((kt + 1) * 64 + sr1) * 128 + sg * 8);
        }
        __syncthreads();                       // Ks ready

        const float ksv = ksreg;
        if (kt + 1 < nkt) ksreg = ksum[(kt + 1) * 64 + rK];

        __builtin_amdgcn_s_setprio(1);
        f32x4 acc = (f32x4)(0.f);
#pragma unroll
        for (int kk = 0; kk < 4; ++kk) {
            bf16x8 b = *(const bf16x8 *)&Ks[rK][((kk * 4 + lq) ^ (rK & 7)) * 8];
            acc = __builtin_amdgcn_mfma_f32_16x16x32_bf16(qfr[kk], b, acc, 0, 0, 0);
        }
        __builtin_amdgcn_s_setprio(0);
        const int j = kt * 64 + rK;
#pragma unroll
        for (int r = 0; r < 4; ++r) {
            const int row = mg * 16 + lq * 4 + r;
            const int i = q0 + row;
            float sv = (2.f * acc[r] - qs[r] - ksv) * C;
            float e = (j <= i) ? exp2f(sv) : 0.f;
            tpart[r] += e;
            Ep[row][(((j >> 3) ^ (row & 7)) << 3) | (j & 7)] = f2bf(e);
        }
    }

    // ---- Causal-tail zeros (fire-and-forget, overlap the reduce) ----
    {
        const int zrow = t >> 4;
        f32x4 z = (f32x4)(0.f);
        for (int c4 = nkt * 16 + (t & 15); c4 < 256; c4 += 16)
            *(f32x4 *)(pout + (size_t)zrow * SLEN + c4 * 4) = z;
    }

    // ---- Row totals: 16-lane reduce -> scratch (reuses Ks) -> registers ----
#pragma unroll
    for (int o = 1; o < 16; o <<= 1)
#pragma unroll
        for (int r = 0; r < 4; ++r) tpart[r] += __shfl_xor(tpart[r], o);
    __syncthreads();                           // all phase-1 Ks reads complete
    if (l16 == 0) {
#pragma unroll
        for (int r = 0; r < 4; ++r) scr[q4 * 32 + mg * 16 + lq * 4 + r] = tpart[r];
    }
    __syncthreads();
    float invP;                                // 1/T for probs-write row t>>4
    {
        const int row = t >> 4;
        const float T = scr[row] + scr[32 + row] + scr[64 + row] + scr[96 + row];
        invP = (q0 + row == 0) ? 0.f : (1.f / T);
    }
    float invC[4];                             // 1/T for ctx rows mg*16+lq*4+r
#pragma unroll
    for (int r = 0; r < 4; ++r) {
        const int row = mg * 16 + lq * 4 + r;
        const float T = scr[row] + scr[32 + row] + scr[64 + row] + scr[96 + row];
        invC[r] = (q0 + row == 0) ? 0.f : (1.f / T);
    }
    __syncthreads();                           // scratch reads done; V may overwrite

    // ---- Phase 2: PV (V prefetched) + interleaved normalized probs writes --
    const int cov = q4 >> 1;
    f32x4 pacc[2];
    pacc[0] = (f32x4)(0.f); pacc[1] = (f32x4)(0.f);
    const unsigned short *vtg = P.vcat_t + (size_t)bh * 128 * SLEN;
    const int vr0 = t >> 3, vg = t & 7;        // V staging d-rows 0..63 / 64..127
    const int vr1 = vr0 + 64;
    bf16x8 vreg0 = *(const bf16x8 *)(vtg + (size_t)vr0 * SLEN + vg * 8);
    bf16x8 vreg1 = *(const bf16x8 *)(vtg + (size_t)vr1 * SLEN + vg * 8);

    for (int kt = 0; kt < nkt; ++kt) {
        __syncthreads();                       // Vt free
        *(bf16x8 *)&Vt[vr0][(vg ^ (vr0 & 7)) * 8] = vreg0;
        *(bf16x8 *)&Vt[vr1][(vg ^ (vr1 & 7)) * 8] = vreg1;
        if (kt + 1 < nkt) {
            vreg0 = *(const bf16x8 *)(vtg + (size_t)vr0 * SLEN + (kt + 1) * 64 + vg * 8);
            vreg1 = *(const bf16x8 *)(vtg + (size_t)vr1 * SLEN + (kt + 1) * 64 + vg * 8);
        }
        __syncthreads();                       // Vt ready

        __builtin_amdgcn_s_setprio(1);
#pragma unroll
        for (int kk = 0; kk < 2; ++kk) {
            const int row = mg * 16 + l16;
            const int gg = (kt * 8) + kk * 4 + lq;
            bf16x8 af = *(const bf16x8 *)&Ep[row][((gg ^ (row & 7)) << 3)];
            if (cov) {                          // cov operand: elementwise square
                u16x8 u = (u16x8)af, sq;
#pragma unroll
                for (int e = 0; e < 8; ++e) {
                    float f = bf2f(u[e]);
                    sq[e] = f2bf(f * f);
                }
                af = (bf16x8)sq;
            }
#pragma unroll
            for (int nf = 0; nf < 2; ++nf) {
                const int d = q4 * 32 + nf * 16 + l16;
                bf16x8 bf = *(const bf16x8 *)&Vt[d][((kk * 4 + lq) ^ (d & 7)) * 8];
                pacc[nf] = __builtin_amdgcn_mfma_f32_16x16x32_bf16(af, bf, pacc[nf], 0, 0, 0);
            }
        }
        __builtin_amdgcn_s_setprio(0);

        // normalized probs write for tile kt (mask only on the diagonal tile)
        {
            const int prow = t >> 4, slot = t & 15;
            const int col = kt * 64 + slot * 4;
            const int g = col >> 3, o4 = (slot & 1) * 4;
            u16x8 v = *(const u16x8 *)&Ep[prow][((g ^ (prow & 7)) << 3)];
            f32x4 ov;
            if (kt == nkt - 1) {
                const int i = q0 + prow;
#pragma unroll
                for (int e = 0; e < 4; ++e)
                    ov[e] = (col + e <= i) ? bf2f(v[o4 + e]) * invP : 0.f;
            } else {
#pragma unroll
                for (int e = 0; e < 4; ++e)
                    ov[e] = bf2f(v[o4 + e]) * invP;
            }
            *(f32x4 *)(pout + (size_t)prow * SLEN + col) = ov;
        }
    }

    unsigned short *dst = cov ? P.ctxc : P.ctxm;
    const int b_ = bh >> 3, h_ = bh & 7;
#pragma unroll
    for (int nf = 0; nf < 2; ++nf) {
#pragma unroll
        for (int r = 0; r < 4; ++r) {
            const int row = mg * 16 + lq * 4 + r;
            const int s_ = q0 + row;
            const float scale = cov ? invC[r] * invC[r] : invC[r];  // /T or /T^2
            dst[((size_t)b_ * SLEN + s_) * HDIM + h_ * 64 + (q4 & 1) * 32 + nf * 16 + l16] =
                f2bf(pacc[nf][r] * scale);
        }
    }
}

// ---------------------------------------------------------------------------
// Fused output GEMM + bias + residual + LayerNorm.
// out = LN(ctx @ WT^T + bias + resid).  Tile 64(M) x 512(N, full row), BK=64.
// 512 threads = 8 waves; round-15: staging via global_load_lds width-16
// (pre-swizzled source, LDS image unchanged).
// ---------------------------------------------------------------------------
__global__ void __launch_bounds__(512, 4) mgemm_ln_k(Args P) {
    const int op = blockIdx.y;
    const unsigned short *Abf = op ? P.ctxc : P.ctxm;
    const unsigned short *WT = P.wt + (size_t)(6 + op) * 262144;
    const float *bias = P.bias[6 + op];
    const float *resid = op ? P.xc : P.xm;
    float *out = op ? P.out_c : P.out_m;
    const int m0 = blockIdx.x * 64;

    __shared__ unsigned short As[64][64];      // 8 KB
    __shared__ unsigned short Bs[512][64];     // 64 KB
    __shared__ float Red[64][4][2];            // 2 KB

    const int t = threadIdx.x;
    const int w = t >> 6, lane = t & 63;
    const int wm = w >> 2, wn = w & 3;         // 2 x 4 waves
    const int l16 = lane & 15, lq = lane >> 4;
    char *AsB = (char *)&As[0][0];
    char *BsB = (char *)&Bs[0][0];

    f32x4 acc[2][8];
#pragma unroll
    for (int mf = 0; mf < 2; ++mf)
#pragma unroll
        for (int nf = 0; nf < 8; ++nf) acc[mf][nf] = (f32x4)(0.f);

    for (int k0 = 0; k0 < 512; k0 += 64) {
        __syncthreads();
        {   // stage A: 64 rows x 8 groups = 512 slots, 1 gload16/thread
            int r = t >> 3, cg = t & 7;
            int sc = (cg ^ (r & 7)) * 8;
            gload16(Abf + (size_t)(m0 + r) * 512 + k0 + sc, AsB + w * 1024);
        }
#pragma unroll
        for (int it = 0; it < 8; ++it) {       // stage B: 512 rows x 8 groups
            int g = t + 512 * it;
            int r = g >> 3, cg = g & 7;
            int sc = (cg ^ (r & 7)) * 8;
            gload16(WT + (size_t)r * 512 + k0 + sc, BsB + it * 8192 + w * 1024);
        }
        __syncthreads();
#pragma unroll
        for (int kk = 0; kk < 2; ++kk) {
            bf16x8 a[2];
#pragma unroll
            for (int mf = 0; mf < 2; ++mf) {
                int r = wm * 32 + mf * 16 + l16;
                a[mf] = *(const bf16x8 *)&As[r][((kk * 4 + lq) ^ (r & 7)) * 8];
            }
#pragma unroll
            for (int nf = 0; nf < 8; ++nf) {
                int rn = wn * 128 + nf * 16 + l16;
                bf16x8 b = *(const bf16x8 *)&Bs[rn][((kk * 4 + lq) ^ (rn & 7)) * 8];
#pragma unroll
                for (int mf = 0; mf < 2; ++mf)
                    acc[mf][nf] = __builtin_amdgcn_mfma_f32_16x16x32_bf16(a[mf], b, acc[mf][nf], 0, 0, 0);
            }
        }
    }

    // epilogue: bias + resid accumulated in place; LN partials per (mf,r)
    float bv[8];
#pragma unroll
    for (int nf = 0; nf < 8; ++nf) bv[nf] = bias[wn * 128 + nf * 16 + l16];

    float s0[2][4], s1[2][4];
#pragma unroll
    for (int mf = 0; mf < 2; ++mf)
#pragma unroll
        for (int r = 0; r < 4; ++r) { s0[mf][r] = 0.f; s1[mf][r] = 0.f; }

#pragma unroll
    for (int mf = 0; mf < 2; ++mf) {
#pragma unroll
        for (int r = 0; r < 4; ++r) {
            const int i = m0 + wm * 32 + mf * 16 + lq * 4 + r;
            const float *rrow = resid + (size_t)i * HDIM + wn * 128 + l16;
#pragma unroll
            for (int nf = 0; nf < 8; ++nf) {
                float x = acc[mf][nf][r] + bv[nf] + rrow[nf * 16];
                acc[mf][nf][r] = x;
                s0[mf][r] += x;
                s1[mf][r] += x * x;
            }
        }
    }
#pragma unroll
    for (int o = 1; o < 16; o <<= 1)
#pragma unroll
        for (int mf = 0; mf < 2; ++mf)
#pragma unroll
            for (int r = 0; r < 4; ++r) {
                s0[mf][r] += __shfl_xor(s0[mf][r], o);
                s1[mf][r] += __shfl_xor(s1[mf][r], o);
            }
    if (l16 == 0) {
#pragma unroll
        for (int mf = 0; mf < 2; ++mf)
#pragma unroll
            for (int r = 0; r < 4; ++r) {
                const int row = wm * 32 + mf * 16 + lq * 4 + r;
                Red[row][wn][0] = s0[mf][r];
                Red[row][wn][1] = s1[mf][r];
            }
    }
    __syncthreads();

    float lnw[8], lnb[8];
#pragma unroll
    for (int nf = 0; nf < 8; ++nf) {
        const int j = wn * 128 + nf * 16 + l16;
        lnw[nf] = P.ln_w[j]; lnb[nf] = P.ln_b[j];
    }
#pragma unroll
    for (int mf = 0; mf < 2; ++mf) {
#pragma unroll
        for (int r = 0; r < 4; ++r) {
            const int row = wm * 32 + mf * 16 + lq * 4 + r;
            const int i = m0 + row;
            const float S  = Red[row][0][0] + Red[row][1][0] + Red[row][2][0] + Red[row][3][0];
            const float SS = Red[row][0][1] + Red[row][1][1] + Red[row][2][1] + Red[row][3][1];
            const float mean = S * (1.f / 512.f);
            const float var = SS * (1.f / 512.f) - mean * mean;
            const float inv = 1.f / sqrtf(var + 1e-12f);
            float *orow = out + (size_t)i * HDIM + wn * 128 + l16;
#pragma unroll
            for (int nf = 0; nf < 8; ++nf)
                orow[nf * 16] = lnw[nf] * ((acc[mf][nf][r] - mean) * inv) + lnb[nf];
        }
    }
}

// ---------------------------------------------------------------------------
extern "C" void kernel_launch(void *const *d_in, const int *in_sizes, int n_in,
                              void *d_out, int out_size, void *d_ws, size_t ws_size,
                              hipStream_t stream) {
    (void)in_sizes; (void)n_in; (void)out_size; (void)ws_size;
    Args P;
    P.xm  = (const float *)d_in[0];
    P.xrm = (const float *)d_in[1];
    P.xc  = (const float *)d_in[2];
    P.xrc = (const float *)d_in[3];
    // d_in[4] = attn_mask: exactly where(causal,0,-1e4); the -1e4 branch
    // underflows to an exact 0 probability, reproduced by causal handling.
    for (int i = 0; i < 8; ++i) {
        P.w[i]    = (const float *)d_in[5 + 2 * i];
        P.bias[i] = (const float *)d_in[6 + 2 * i];
    }
    P.ln_w = (const float *)d_in[21];
    P.ln_b = (const float *)d_in[22];

    char *ws = (char *)d_ws;
    P.xbf    = (unsigned short *)(ws);
    P.vcat_t = (unsigned short *)(ws);                 // alias xbf[0..2) (dead)
    P.ctxm   = (unsigned short *)(ws + 33554432);      // alias xbf[2..3) (dead)
    P.ctxc   = (unsigned short *)(ws + 50331648);      // alias xbf[3..4) (dead)
    P.wt     = (unsigned short *)(ws + 67108864);
    P.sums   = (float *)(ws + 71303168);
    P.qcat   = (unsigned short *)(ws + 72351744);      // live through flash_k
    P.kcat   = (unsigned short *)(ws + 105906176);
    P.vcat   = (unsigned short *)(ws + 139460608);

    P.out_m = (float *)d_out;
    P.out_c = (float *)d_out + 8388608;
    P.probs = (float *)d_out + 16777216;

    cvt_inputs_k<<<dim3(4096, 4), dim3(256), 0, stream>>>(P);
    wtrans_k<<<dim3(64, 8), dim3(256), 0, stream>>>(P);
    mgemm0_k<<<dim3(4, 128, 6), dim3(256), 0, stream>>>(P);
    vtrans_k<<<dim3(8, 128), dim3(256), 0, stream>>>(P);
    rowsum_k<<<dim3(65536), dim3(256), 0, stream>>>(P);
    flash_k<<<dim3(128, 32), dim3(512), 0, stream>>>(P);
    mgemm_ln_k<<<dim3(256, 2), dim3(512), 0, stream>>>(P);
}

// Round 16
// 448.689 us; speedup vs baseline: 1.1677x; 1.0397x over previous
//
#include <hip/hip_runtime.h>
#include <math.h>

// Problem constants
#define SLEN 1024
#define NH 8
#define DH 64
#define HDIM 512
#define BATCH 16
#define NROWS (BATCH * SLEN)          // 16384
#define BHN (BATCH * NH)              // 128
#define BHROWS (BHN * SLEN)           // 131072

typedef short bf16x8 __attribute__((ext_vector_type(8)));
typedef unsigned short u16x8 __attribute__((ext_vector_type(8)));
typedef unsigned short u16x4 __attribute__((ext_vector_type(4)));
typedef float f32x4 __attribute__((ext_vector_type(4)));

__device__ __forceinline__ unsigned short f2bf(float f) {
    unsigned u = __float_as_uint(f);
    u += 0x7fffu + ((u >> 16) & 1u);           // RNE
    return (unsigned short)(u >> 16);
}
__device__ __forceinline__ float bf2f(unsigned short h) {
    return __uint_as_float(((unsigned)h) << 16);
}

// Async global->LDS 16B copy: per-lane global src, wave-uniform LDS base
// (HW writes at base + lane*16). Drained by the vmcnt(0) in __syncthreads.
__device__ __forceinline__ void gload16(const void *g, void *l) {
    __builtin_amdgcn_global_load_lds(
        (const __attribute__((address_space(1))) unsigned int *)g,
        (__attribute__((address_space(3))) unsigned int *)l,
        16, 0, 0);
}

// ---------------------------------------------------------------------------
// Workspace layout (BYTE offsets). Peak 174,063,616 B (round-1 used 202 MB OK).
//   xbf      @ 0          : 4 x 16,777,216 (xm,xrm,xc,xrc bf16) [live thru mgemm0]
//     ctxm   @ 33,554,432 (aliases xbf[2], written by flash, after mgemm0 reads)
//     ctxc   @ 50,331,648 (aliases xbf[3])
//   wt       @ 67,108,864 : 8 x 524,288 (W^T bf16 [n][k])
//   sums     @ 71,303,168 : 2,097,152 fp32 partials: qm | qc | km | kc
//   qcat     @ 73,400,320 : 33,554,432 bf16 [bh][s][128]
//   kcat     @106,954,752 : 33,554,432
//   vcat_t   @140,509,184 : 33,554,432 bf16 [bh][d][1024] (written by mgemm0)
// ---------------------------------------------------------------------------
struct Args {
    const float *xm, *xrm, *xc, *xrc;
    const float *w[8], *bias[8];
    const float *ln_w, *ln_b;
    unsigned short *xbf, *wt;
    float *sums;
    unsigned short *qcat, *kcat, *vcat_t, *ctxm, *ctxc;
    float *out_m, *out_c, *probs;
};

// ---------------------------------------------------------------------------
// Convert the 4 fp32 activation inputs to bf16. grid (4096, 4) x 256.
// ---------------------------------------------------------------------------
__global__ void __launch_bounds__(256) cvt_inputs_k(Args P) {
    const int which = blockIdx.y;
    const float *s = which == 0 ? P.xm : which == 1 ? P.xrm : which == 2 ? P.xc : P.xrc;
    unsigned short *d = P.xbf + (size_t)which * 8388608;
    const long long i = ((long long)blockIdx.x * 256 + threadIdx.x) * 8;
    if (i >= 8388608) return;          // safety guard
    float4 a = *(const float4 *)(s + i);
    float4 b = *(const float4 *)(s + i + 4);
    u16x8 o;
    o[0] = f2bf(a.x); o[1] = f2bf(a.y); o[2] = f2bf(a.z); o[3] = f2bf(a.w);
    o[4] = f2bf(b.x); o[5] = f2bf(b.y); o[6] = f2bf(b.z); o[7] = f2bf(b.w);
    *(u16x8 *)(d + i) = o;
}

// ---------------------------------------------------------------------------
// Transpose+convert the 8 weight matrices: WT[n][k] = bf16(W[k][n]).
// ---------------------------------------------------------------------------
__global__ void __launch_bounds__(256) wtrans_k(Args P) {
    const int op = blockIdx.y;
    const float *W = P.w[op];
    unsigned short *WT = P.wt + (size_t)op * 262144;
    const int kt = blockIdx.x >> 3, nt = blockIdx.x & 7;
    __shared__ float Ws[64][65];
    const int t = threadIdx.x;
#pragma unroll
    for (int it = 0; it < 4; ++it) {
        int g = t + 256 * it;
        int k = g >> 4, n4 = (g & 15) * 4;
        float4 v = *(const float4 *)(W + (size_t)(kt * 64 + k) * 512 + nt * 64 + n4);
        Ws[k][n4] = v.x; Ws[k][n4 + 1] = v.y; Ws[k][n4 + 2] = v.z; Ws[k][n4 + 3] = v.w;
    }
    __syncthreads();
#pragma unroll
    for (int it = 0; it < 2; ++it) {
        int g = t + 256 * it;
        int n = g >> 3, kg = (g & 7) * 8;
        u16x8 o;
#pragma unroll
        for (int e = 0; e < 8; ++e) o[e] = f2bf(Ws[kg + e][n]);
        *(u16x8 *)(WT + (size_t)(nt * 64 + n) * 512 + kt * 64 + kg) = o;
    }
}

// ---------------------------------------------------------------------------
// Projection GEMMs (bf16 MFMA), 128x128 tile, BK=64, 4 waves (2x2, 64x64).
// XCD-aware swizzle; global_load_lds staging with pre-swizzled source.
// Round-16 fusions:
//  - ops 2/5 (mv, cv) write DIRECTLY to vcat_t[bh][d][s] (8B u16x4 stores of
//    4 consecutive s) -- vtrans_k deleted; bytes identical to its output.
//  - ops 0/1/3/4 emit per-row partial sums of bf16(v)^2 over their 64-dim
//    head-half (shfl reduce, one writer/row, no atomics) -- rowsum_k deleted.
// ---------------------------------------------------------------------------
__global__ void __launch_bounds__(256) mgemm0_k(Args P) {
    const int op = blockIdx.z;
    const int srcidx[6] = {0, 0, 1, 2, 2, 3};
    const unsigned short *Abf = P.xbf + (size_t)srcidx[op] * 8388608;
    const unsigned short *WT = P.wt + (size_t)op * 262144;
    const float *bias = P.bias[op];
    unsigned short *dstb; int doff, act;
    switch (op) {
        case 0: dstb = P.qcat; doff = 0;  act = 0; break;
        case 1: dstb = P.kcat; doff = 0;  act = 0; break;
        case 2: dstb = nullptr; doff = 0;  act = 0; break;   // -> vcat_t
        case 3: dstb = P.qcat; doff = 64; act = 1; break;
        case 4: dstb = P.kcat; doff = 64; act = 1; break;
        default:dstb = nullptr; doff = 64; act = 2; break;   // -> vcat_t
    }
    // XCD swizzle (dispatch idx % 8 == XCD; 512 blocks per op, 512%8==0)
    const int lin = blockIdx.y * 4 + blockIdx.x;       // 0..511
    const int xcd = lin & 7, idx = lin >> 3;           // idx 0..63
    const int m0 = (xcd * 16 + (idx >> 2)) * 128;
    const int n0 = (idx & 3) * 128;

    __shared__ unsigned short As[128][64];
    __shared__ unsigned short Bs[128][64];
    const int t = threadIdx.x;
    const int wid = t >> 6, lane = t & 63;
    const int wm = wid >> 1, wn = wid & 1;
    const int l16 = lane & 15, lq = lane >> 4;
    char *AsB = (char *)&As[0][0];
    char *BsB = (char *)&Bs[0][0];

    f32x4 acc[4][4];
#pragma unroll
    for (int i = 0; i < 4; ++i)
#pragma unroll
        for (int j = 0; j < 4; ++j) acc[i][j] = (f32x4)(0.f);

    for (int k0 = 0; k0 < 512; k0 += 64) {
        __syncthreads();
#pragma unroll
        for (int it = 0; it < 4; ++it) {
            int g = t + 256 * it;
            int r = g >> 3, cg = g & 7;
            int sc = (cg ^ (r & 7)) * 8;       // pre-swizzled source group
            gload16(Abf + (size_t)(m0 + r) * 512 + k0 + sc, AsB + it * 4096 + wid * 1024);
            gload16(WT + (size_t)(n0 + r) * 512 + k0 + sc, BsB + it * 4096 + wid * 1024);
        }
        __syncthreads();
#pragma unroll
        for (int kk = 0; kk < 2; ++kk) {
            bf16x8 a[4], b[4];
#pragma unroll
            for (int mf = 0; mf < 4; ++mf) {
                int r = wm * 64 + mf * 16 + l16;
                int cg = kk * 4 + lq;
                a[mf] = *(const bf16x8 *)&As[r][(cg ^ (r & 7)) * 8];
            }
#pragma unroll
            for (int nf = 0; nf < 4; ++nf) {
                int r = wn * 64 + nf * 16 + l16;
                int cg = kk * 4 + lq;
                b[nf] = *(const bf16x8 *)&Bs[r][(cg ^ (r & 7)) * 8];
            }
#pragma unroll
            for (int mf = 0; mf < 4; ++mf)
#pragma unroll
                for (int nf = 0; nf < 4; ++nf)
                    acc[mf][nf] = __builtin_amdgcn_mfma_f32_16x16x32_bf16(a[mf], b[nf], acc[mf][nf], 0, 0, 0);
        }
    }

    const int b_ = m0 >> 10;                   // batch (block spans one b_)
    const int srow0 = m0 & 1023;
    const bool isV = (op == 2 || op == 5);

    if (isV) {
        unsigned short *vt = P.vcat_t;
#pragma unroll
        for (int mf = 0; mf < 4; ++mf) {
#pragma unroll
            for (int nf = 0; nf < 4; ++nf) {
                const int j = n0 + wn * 64 + nf * 16 + l16;
                const int h_ = j >> 6, dd = doff + (j & 63);
                u16x4 pk;
#pragma unroll
                for (int r = 0; r < 4; ++r) {
                    float v = acc[mf][nf][r] + bias[j];
                    if (act == 2) v = v > 0.f ? v + 1.f : expf(v);
                    pk[r] = f2bf(v);
                }
                const int s_ = srow0 + wm * 64 + mf * 16 + lq * 4;
                *(u16x4 *)(vt + ((size_t)(b_ * NH + h_) * 128 + dd) * SLEN + s_) = pk;
            }
        }
    } else {
        float rs[4][4];
#pragma unroll
        for (int mf = 0; mf < 4; ++mf)
#pragma unroll
            for (int r = 0; r < 4; ++r) rs[mf][r] = 0.f;

#pragma unroll
        for (int mf = 0; mf < 4; ++mf) {
#pragma unroll
            for (int nf = 0; nf < 4; ++nf) {
                const int j = n0 + wn * 64 + nf * 16 + l16;
                const int h_ = j >> 6, d_ = j & 63;
#pragma unroll
                for (int r = 0; r < 4; ++r) {
                    float v = acc[mf][nf][r] + bias[j];
                    if (act == 1) {
                        float e = v > 0.f ? v + 1.f : expf(v);
                        v = sqrtf(fmaxf(e, 1e-24f));
                    }
                    unsigned short hb = f2bf(v);
                    const int s_ = srow0 + wm * 64 + mf * 16 + lq * 4 + r;
                    dstb[((size_t)(b_ * NH + h_) * SLEN + s_) * 128 + doff + d_] = hb;
                    const float vb = bf2f(hb);
                    rs[mf][r] += vb * vb;      // matches old rowsum (bf16 values)
                }
            }
        }
        // partial row-sums over this 64-dim head-half; one writer per row.
        // layout: qm @0, qc @BHROWS, km @2*BHROWS, kc @3*BHROWS
        float *sdst = P.sums +
            (size_t)((op == 0) ? 0 : (op == 3) ? 1 : (op == 1) ? 2 : 3) * BHROWS;
        const int h_ = (n0 >> 6) + wn;
#pragma unroll
        for (int mf = 0; mf < 4; ++mf) {
#pragma unroll
            for (int r = 0; r < 4; ++r) {
                float x = rs[mf][r];
                x += __shfl_xor(x, 1);
                x += __shfl_xor(x, 2);
                x += __shfl_xor(x, 4);
                x += __shfl_xor(x, 8);
                if (l16 == 0) {
                    const int s_ = srow0 + wm * 64 + mf * 16 + lq * 4 + r;
                    sdst[(size_t)(b_ * NH + h_) * SLEN + s_] = x;
                }
            }
        }
    }
}

// ---------------------------------------------------------------------------
// Fused flash attention (round-13 structure + exp2f + setprio): 32-row
// q-tiles, 512 thr = 8 waves, 80 KB LDS -> 2 blocks/CU, K/V reg-prefetch,
// interleaved probs writes, in-flash causal-tail zeros.
// Round-16: qsum/ksum read as qm+qc / km+kc partials.
// ---------------------------------------------------------------------------
__global__ void __launch_bounds__(512, 4) flash_k(Args P) {
    const int bh = blockIdx.x;
    const int qt = 31 - (int)blockIdx.y;       // 32-row q tiles, longest first
    const int q0 = qt * 32;
    __shared__ unsigned short Ep[32][1024];    // 64 KB
    __shared__ unsigned short Ks[64][128];     // 16 KB (aliases: T scratch, V tile)
    unsigned short (*Vt)[64] = reinterpret_cast<unsigned short (*)[64]>(&Ks[0][0]);
    float *scr = reinterpret_cast<float *>(&Ks[0][0]);   // [4][32] T partials

    const int t = threadIdx.x;
    const int w = t >> 6, lane = t & 63;
    const int l16 = lane & 15, lq = lane >> 4;
    const int mg = w >> 2, q4 = w & 3;

    const unsigned short *qc = P.qcat + (size_t)bh * SLEN * 128;
    const unsigned short *kc = P.kcat + (size_t)bh * SLEN * 128;
    const float *qm_p = P.sums + (size_t)bh * SLEN;
    const float *qc_p = qm_p + BHROWS;
    const float *km_p = P.sums + 2 * (size_t)BHROWS + (size_t)bh * SLEN;
    const float *kc_p = km_p + BHROWS;
    float *pout = P.probs + ((size_t)bh * SLEN + q0) * SLEN;

    // Q fragments: row = q0 + mg*16 + l16, k-group kk*4+lq (covers 128 dims).
    const unsigned short *qrow = qc + (size_t)(q0 + mg * 16 + l16) * 128;
    bf16x8 qfr[4];
#pragma unroll
    for (int kk = 0; kk < 4; ++kk) qfr[kk] = *(const bf16x8 *)(qrow + (kk * 4 + lq) * 8);
    float qs[4];
#pragma unroll
    for (int r = 0; r < 4; ++r) {
        const int i = q0 + mg * 16 + lq * 4 + r;
        qs[r] = qm_p[i] + qc_p[i];
    }

    const int nkt = (q0 >> 6) + 1;             // 64-wide k tiles covering <= q0+31
    const int rK = q4 * 16 + l16;
    float tpart[4] = {0.f, 0.f, 0.f, 0.f};
    const float C = 0.18033688f;               // 0.125 * log2(e)

    // ---- Phase 1: masked exp(scores) into the panel, K prefetched ----
    const int sr0 = t >> 4, sg = t & 15;       // K staging rows 0..31 / 32..63
    const int sr1 = sr0 + 32;
    bf16x8 kreg0 = *(const bf16x8 *)(kc + (size_t)sr0 * 128 + sg * 8);
    bf16x8 kreg1 = *(const bf16x8 *)(kc + (size_t)sr1 * 128 + sg * 8);
    float ksreg = km_p[rK] + kc_p[rK];

    for (int kt = 0; kt < nkt; ++kt) {
        __syncthreads();                       // Ks free (prev reads done)
        *(bf16x8 *)&Ks[sr0][(sg ^ (sr0 & 7)) * 8] = kreg0;
        *(bf16x8 *)&Ks[sr1][(sg ^ (sr1 & 7)) * 8] = kreg1;
        if (kt + 1 < nkt) {
            kreg0 = *(const bf16x8 *)(kc + (size_t)((kt + 1) * 64 + sr0) * 128 + sg * 8);
            kreg1 = *(const bf16x8 *)(kc + (size_t)((kt + 1) * 64 + sr1) * 128 + sg * 8);
        }
        __syncthreads();                       // Ks ready

        const float ksv = ksreg;
        if (kt + 1 < nkt) {
            const int jn = (kt + 1) * 64 + rK;
            ksreg = km_p[jn] + kc_p[jn];
        }

        __builtin_amdgcn_s_setprio(1);
        f32x4 acc = (f32x4)(0.f);
#pragma unroll
        for (int kk = 0; kk < 4; ++kk) {
            bf16x8 b = *(const bf16x8 *)&Ks[rK][((kk * 4 + lq) ^ (rK & 7)) * 8];
            acc = __builtin_amdgcn_mfma_f32_16x16x32_bf16(qfr[kk], b, acc, 0, 0, 0);
        }
        __builtin_amdgcn_s_setprio(0);
        const int j = kt * 64 + rK;
#pragma unroll
        for (int r = 0; r < 4; ++r) {
            const int row = mg * 16 + lq * 4 + r;
            const int i = q0 + row;
            float sv = (2.f * acc[r] - qs[r] - ksv) * C;
            float e = (j <= i) ? exp2f(sv) : 0.f;
            tpart[r] += e;
            Ep[row][(((j >> 3) ^ (row & 7)) << 3) | (j & 7)] = f2bf(e);
        }
    }

    // ---- Causal-tail zeros (fire-and-forget, overlap the reduce) ----
    {
        const int zrow = t >> 4;
        f32x4 z = (f32x4)(0.f);
        for (int c4 = nkt * 16 + (t & 15); c4 < 256; c4 += 16)
            *(f32x4 *)(pout + (size_t)zrow * SLEN + c4 * 4) = z;
    }

    // ---- Row totals: 16-lane reduce -> scratch (reuses Ks) -> registers ----
#pragma unroll
    for (int o = 1; o < 16; o <<= 1)
#pragma unroll
        for (int r = 0; r < 4; ++r) tpart[r] += __shfl_xor(tpart[r], o);
    __syncthreads();                           // all phase-1 Ks reads complete
    if (l16 == 0) {
#pragma unroll
        for (int r = 0; r < 4; ++r) scr[q4 * 32 + mg * 16 + lq * 4 + r] = tpart[r];
    }
    __syncthreads();
    float invP;                                // 1/T for probs-write row t>>4
    {
        const int row = t >> 4;
        const float T = scr[row] + scr[32 + row] + scr[64 + row] + scr[96 + row];
        invP = (q0 + row == 0) ? 0.f : (1.f / T);
    }
    float invC[4];                             // 1/T for ctx rows mg*16+lq*4+r
#pragma unroll
    for (int r = 0; r < 4; ++r) {
        const int row = mg * 16 + lq * 4 + r;
        const float T = scr[row] + scr[32 + row] + scr[64 + row] + scr[96 + row];
        invC[r] = (q0 + row == 0) ? 0.f : (1.f / T);
    }
    __syncthreads();                           // scratch reads done; V may overwrite

    // ---- Phase 2: PV (V prefetched) + interleaved normalized probs writes --
    const int cov = q4 >> 1;
    f32x4 pacc[2];
    pacc[0] = (f32x4)(0.f); pacc[1] = (f32x4)(0.f);
    const unsigned short *vtg = P.vcat_t + (size_t)bh * 128 * SLEN;
    const int vr0 = t >> 3, vg = t & 7;        // V staging d-rows 0..63 / 64..127
    const int vr1 = vr0 + 64;
    bf16x8 vreg0 = *(const bf16x8 *)(vtg + (size_t)vr0 * SLEN + vg * 8);
    bf16x8 vreg1 = *(const bf16x8 *)(vtg + (size_t)vr1 * SLEN + vg * 8);

    for (int kt = 0; kt < nkt; ++kt) {
        __syncthreads();                       // Vt free
        *(bf16x8 *)&Vt[vr0][(vg ^ (vr0 & 7)) * 8] = vreg0;
        *(bf16x8 *)&Vt[vr1][(vg ^ (vr1 & 7)) * 8] = vreg1;
        if (kt + 1 < nkt) {
            vreg0 = *(const bf16x8 *)(vtg + (size_t)vr0 * SLEN + (kt + 1) * 64 + vg * 8);
            vreg1 = *(const bf16x8 *)(vtg + (size_t)vr1 * SLEN + (kt + 1) * 64 + vg * 8);
        }
        __syncthreads();                       // Vt ready

        __builtin_amdgcn_s_setprio(1);
#pragma unroll
        for (int kk = 0; kk < 2; ++kk) {
            const int row = mg * 16 + l16;
            const int gg = (kt * 8) + kk * 4 + lq;
            bf16x8 af = *(const bf16x8 *)&Ep[row][((gg ^ (row & 7)) << 3)];
            if (cov) {                          // cov operand: elementwise square
                u16x8 u = (u16x8)af, sq;
#pragma unroll
                for (int e = 0; e < 8; ++e) {
                    float f = bf2f(u[e]);
                    sq[e] = f2bf(f * f);
                }
                af = (bf16x8)sq;
            }
#pragma unroll
            for (int nf = 0; nf < 2; ++nf) {
                const int d = q4 * 32 + nf * 16 + l16;
                bf16x8 bf = *(const bf16x8 *)&Vt[d][((kk * 4 + lq) ^ (d & 7)) * 8];
                pacc[nf] = __builtin_amdgcn_mfma_f32_16x16x32_bf16(af, bf, pacc[nf], 0, 0, 0);
            }
        }
        __builtin_amdgcn_s_setprio(0);

        // normalized probs write for tile kt (mask only on the diagonal tile)
        {
            const int prow = t >> 4, slot = t & 15;
            const int col = kt * 64 + slot * 4;
            const int g = col >> 3, o4 = (slot & 1) * 4;
            u16x8 v = *(const u16x8 *)&Ep[prow][((g ^ (prow & 7)) << 3)];
            f32x4 ov;
            if (kt == nkt - 1) {
                const int i = q0 + prow;
#pragma unroll
                for (int e = 0; e < 4; ++e)
                    ov[e] = (col + e <= i) ? bf2f(v[o4 + e]) * invP : 0.f;
            } else {
#pragma unroll
                for (int e = 0; e < 4; ++e)
                    ov[e] = bf2f(v[o4 + e]) * invP;
            }
            *(f32x4 *)(pout + (size_t)prow * SLEN + col) = ov;
        }
    }

    unsigned short *dst = cov ? P.ctxc : P.ctxm;
    const int b_ = bh >> 3, h_ = bh & 7;
#pragma unroll
    for (int nf = 0; nf < 2; ++nf) {
#pragma unroll
        for (int r = 0; r < 4; ++r) {
            const int row = mg * 16 + lq * 4 + r;
            const int s_ = q0 + row;
            const float scale = cov ? invC[r] * invC[r] : invC[r];  // /T or /T^2
            dst[((size_t)b_ * SLEN + s_) * HDIM + h_ * 64 + (q4 & 1) * 32 + nf * 16 + l16] =
                f2bf(pacc[nf][r] * scale);
        }
    }
}

// ---------------------------------------------------------------------------
// Fused output GEMM + bias + residual + LayerNorm.
// out = LN(ctx @ WT^T + bias + resid).  Tile 64(M) x 512(N, full row), BK=64.
// 512 threads = 8 waves; global_load_lds staging (pre-swizzled source).
// grid (256 m-tiles, 2 ops).
// ---------------------------------------------------------------------------
__global__ void __launch_bounds__(512, 4) mgemm_ln_k(Args P) {
    const int op = blockIdx.y;
    const unsigned short *Abf = op ? P.ctxc : P.ctxm;
    const unsigned short *WT = P.wt + (size_t)(6 + op) * 262144;
    const float *bias = P.bias[6 + op];
    const float *resid = op ? P.xc : P.xm;
    float *out = op ? P.out_c : P.out_m;
    const int m0 = blockIdx.x * 64;

    __shared__ unsigned short As[64][64];      // 8 KB
    __shared__ unsigned short Bs[512][64];     // 64 KB
    __shared__ float Red[64][4][2];            // 2 KB

    const int t = threadIdx.x;
    const int w = t >> 6, lane = t & 63;
    const int wm = w >> 2, wn = w & 3;         // 2 x 4 waves
    const int l16 = lane & 15, lq = lane >> 4;
    char *AsB = (char *)&As[0][0];
    char *BsB = (char *)&Bs[0][0];

    f32x4 acc[2][8];
#pragma unroll
    for (int mf = 0; mf < 2; ++mf)
#pragma unroll
        for (int nf = 0; nf < 8; ++nf) acc[mf][nf] = (f32x4)(0.f);

    for (int k0 = 0; k0 < 512; k0 += 64) {
        __syncthreads();
        {   // stage A: 64 rows x 8 groups = 512 slots, 1 gload16/thread
            int r = t >> 3, cg = t & 7;
            int sc = (cg ^ (r & 7)) * 8;
            gload16(Abf + (size_t)(m0 + r) * 512 + k0 + sc, AsB + w * 1024);
        }
#pragma unroll
        for (int it = 0; it < 8; ++it) {       // stage B: 512 rows x 8 groups
            int g = t + 512 * it;
            int r = g >> 3, cg = g & 7;
            int sc = (cg ^ (r & 7)) * 8;
            gload16(WT + (size_t)r * 512 + k0 + sc, BsB + it * 8192 + w * 1024);
        }
        __syncthreads();
#pragma unroll
        for (int kk = 0; kk < 2; ++kk) {
            bf16x8 a[2];
#pragma unroll
            for (int mf = 0; mf < 2; ++mf) {
                int r = wm * 32 + mf * 16 + l16;
                a[mf] = *(const bf16x8 *)&As[r][((kk * 4 + lq) ^ (r & 7)) * 8];
            }
#pragma unroll
            for (int nf = 0; nf < 8; ++nf) {
                int rn = wn * 128 + nf * 16 + l16;
                bf16x8 b = *(const bf16x8 *)&Bs[rn][((kk * 4 + lq) ^ (rn & 7)) * 8];
#pragma unroll
                for (int mf = 0; mf < 2; ++mf)
                    acc[mf][nf] = __builtin_amdgcn_mfma_f32_16x16x32_bf16(a[mf], b, acc[mf][nf], 0, 0, 0);
            }
        }
    }

    // epilogue: bias + resid accumulated in place; LN partials per (mf,r)
    float bv[8];
#pragma unroll
    for (int nf = 0; nf < 8; ++nf) bv[nf] = bias[wn * 128 + nf * 16 + l16];

    float s0[2][4], s1[2][4];
#pragma unroll
    for (int mf = 0; mf < 2; ++mf)
#pragma unroll
        for (int r = 0; r < 4; ++r) { s0[mf][r] = 0.f; s1[mf][r] = 0.f; }

#pragma unroll
    for (int mf = 0; mf < 2; ++mf) {
#pragma unroll
        for (int r = 0; r < 4; ++r) {
            const int i = m0 + wm * 32 + mf * 16 + lq * 4 + r;
            const float *rrow = resid + (size_t)i * HDIM + wn * 128 + l16;
#pragma unroll
            for (int nf = 0; nf < 8; ++nf) {
                float x = acc[mf][nf][r] + bv[nf] + rrow[nf * 16];
                acc[mf][nf][r] = x;
                s0[mf][r] += x;
                s1[mf][r] += x * x;
            }
        }
    }
#pragma unroll
    for (int o = 1; o < 16; o <<= 1)
#pragma unroll
        for (int mf = 0; mf < 2; ++mf)
#pragma unroll
            for (int r = 0; r < 4; ++r) {
                s0[mf][r] += __shfl_xor(s0[mf][r], o);
                s1[mf][r] += __shfl_xor(s1[mf][r], o);
            }
    if (l16 == 0) {
#pragma unroll
        for (int mf = 0; mf < 2; ++mf)
#pragma unroll
            for (int r = 0; r < 4; ++r) {
                const int row = wm * 32 + mf * 16 + lq * 4 + r;
                Red[row][wn][0] = s0[mf][r];
                Red[row][wn][1] = s1[mf][r];
            }
    }
    __syncthreads();

    float lnw[8], lnb[8];
#pragma unroll
    for (int nf = 0; nf < 8; ++nf) {
        const int j = wn * 128 + nf * 16 + l16;
        lnw[nf] = P.ln_w[j]; lnb[nf] = P.ln_b[j];
    }
#pragma unroll
    for (int mf = 0; mf < 2; ++mf) {
#pragma unroll
        for (int r = 0; r < 4; ++r) {
            const int row = wm * 32 + mf * 16 + lq * 4 + r;
            const int i = m0 + row;
            const float S  = Red[row][0][0] + Red[row][1][0] + Red[row][2][0] + Red[row][3][0];
            const float SS = Red[row][0][1] + Red[row][1][1] + Red[row][2][1] + Red[row][3][1];
            const float mean = S * (1.f / 512.f);
            const float var = SS * (1.f / 512.f) - mean * mean;
            const float inv = 1.f / sqrtf(var + 1e-12f);
            float *orow = out + (size_t)i * HDIM + wn * 128 + l16;
#pragma unroll
            for (int nf = 0; nf < 8; ++nf)
                orow[nf * 16] = lnw[nf] * ((acc[mf][nf][r] - mean) * inv) + lnb[nf];
        }
    }
}

// ---------------------------------------------------------------------------
extern "C" void kernel_launch(void *const *d_in, const int *in_sizes, int n_in,
                              void *d_out, int out_size, void *d_ws, size_t ws_size,
                              hipStream_t stream) {
    (void)in_sizes; (void)n_in; (void)out_size; (void)ws_size;
    Args P;
    P.xm  = (const float *)d_in[0];
    P.xrm = (const float *)d_in[1];
    P.xc  = (const float *)d_in[2];
    P.xrc = (const float *)d_in[3];
    // d_in[4] = attn_mask: exactly where(causal,0,-1e4); the -1e4 branch
    // underflows to an exact 0 probability, reproduced by causal handling.
    for (int i = 0; i < 8; ++i) {
        P.w[i]    = (const float *)d_in[5 + 2 * i];
        P.bias[i] = (const float *)d_in[6 + 2 * i];
    }
    P.ln_w = (const float *)d_in[21];
    P.ln_b = (const float *)d_in[22];

    char *ws = (char *)d_ws;
    P.xbf    = (unsigned short *)(ws);                 // live through mgemm0
    P.ctxm   = (unsigned short *)(ws + 33554432);      // alias xbf[2] (flash writes after mgemm0)
    P.ctxc   = (unsigned short *)(ws + 50331648);      // alias xbf[3]
    P.wt     = (unsigned short *)(ws + 67108864);
    P.sums   = (float *)(ws + 71303168);               // qm|qc|km|kc partials, 2 MB
    P.qcat   = (unsigned short *)(ws + 73400320);
    P.kcat   = (unsigned short *)(ws + 106954752);
    P.vcat_t = (unsigned short *)(ws + 140509184);     // written by mgemm0 ops 2/5

    P.out_m = (float *)d_out;
    P.out_c = (float *)d_out + 8388608;
    P.probs = (float *)d_out + 16777216;

    cvt_inputs_k<<<dim3(4096, 4), dim3(256), 0, stream>>>(P);
    wtrans_k<<<dim3(64, 8), dim3(256), 0, stream>>>(P);
    mgemm0_k<<<dim3(4, 128, 6), dim3(256), 0, stream>>>(P);
    flash_k<<<dim3(128, 32), dim3(512), 0, stream>>>(P);
    mgemm_ln_k<<<dim3(256, 2), dim3(512), 0, stream>>>(P);
}